// Round 6
// baseline (162.911 us; speedup 1.0000x reference)
//
#include <hip/hip_runtime.h>
#include <hip/hip_bf16.h>

typedef __attribute__((ext_vector_type(8))) __bf16 bf16x8;
typedef __attribute__((ext_vector_type(4))) __bf16 bf16x4;
typedef __attribute__((ext_vector_type(4))) float f32x4;

constexpr int S_LEN = 4096;
constexpr int H = 8;
constexpr int HKV = 2;
constexpr int D = 64;
constexpr int BK = 64;               // keys per tile
constexpr int QW = 32;               // q rows per wave (2 halves of 16)
constexpr int WAVES = 4;             // 128 q rows per block
constexpr int QB_ROWS = QW * WAVES;  // 128
constexpr int NQB = S_LEN / QB_ROWS; // 32
// exp2-domain: scores scaled by 1/sqrt(64) * log2(e)
constexpr float QSCALE = 0.125f * 1.44269504088896f;
constexpr float RTHR = 8.0f;         // defer-max threshold (log2 units)

// XOR swizzle for [*][64] bf16 tiles; f(row)=((row>>2)^row)&7 spreads both
// stride-1 and stride-4 row patterns across 8 16B slots. Preserves 16B chunks.
__device__ __forceinline__ int swz(int row, int col) {
  return (row * 64 + col) ^ ((((row >> 2) ^ row) & 7) << 3);
}

__device__ __forceinline__ bf16x8 load8_scaled(const float* p, float scale) {
  f32x4 a = *reinterpret_cast<const f32x4*>(p);
  f32x4 b = *reinterpret_cast<const f32x4*>(p + 4);
  bf16x8 r;
  r[0] = (__bf16)(a[0] * scale); r[1] = (__bf16)(a[1] * scale);
  r[2] = (__bf16)(a[2] * scale); r[3] = (__bf16)(a[3] * scale);
  r[4] = (__bf16)(b[0] * scale); r[5] = (__bf16)(b[1] * scale);
  r[6] = (__bf16)(b[2] * scale); r[7] = (__bf16)(b[3] * scale);
  return r;
}

// CHUNK = 1<<LOG2C keys per split chunk. Compact grid: widx enumerates
// (qb, c) pairs heavy-qb-first with exactly cmax(qb)+1 chunks per qb.
template <int LOG2C, bool SPLIT>
__global__ __launch_bounds__(256, 4) void gqa_fwd_kernel(
    const float* __restrict__ q, const float* __restrict__ k,
    const float* __restrict__ v, float* __restrict__ out,
    __bf16* __restrict__ po, float* __restrict__ ml) {
  constexpr int TPC = (1 << LOG2C) / BK;  // tiles per full chunk

  const int tid  = threadIdx.x;
  const int lane = tid & 63;
  const int wid  = tid >> 6;
  const int r    = lane & 15;
  const int g4   = lane >> 4;

  const int h = blockIdx.x & 7;
  const int widx = blockIdx.x >> 3;
  int qb = 0, c = 0;
  {
    int acc0 = 0;
    for (int qq = NQB - 1; qq >= 0; --qq) {   // heavy q-blocks first
      const int n = ((qq * QB_ROWS + QB_ROWS - 1) >> LOG2C) + 1;
      if (widx < acc0 + n) { qb = qq; c = widx - acc0; break; }
      acc0 += n;
    }
  }
  const int cmax = (qb * QB_ROWS + QB_ROWS - 1) >> LOG2C;
  const int hkv = h >> 2;
  const int q0w = qb * QB_ROWS + wid * QW;            // wave's first q row
  const int nt  = (c < cmax) ? TPC : (2 * (qb + 1) - TPC * cmax);
  const int kb0 = c << LOG2C;

  __shared__ __bf16 klds[2][64 * 64];          // K tile [kv][d], swizzled
  __shared__ __bf16 vlds[2][64 * 64];          // V^T tile [d][kv], swizzled
  __shared__ __bf16 plds[WAVES][16 * 64];      // P^T scratch, reused per half

  // ---- Q B-fragments (held), pre-scaled into exp2 domain ----
  bf16x8 qf[2][2];
#pragma unroll
  for (int h2 = 0; h2 < 2; ++h2)
#pragma unroll
    for (int ks = 0; ks < 2; ++ks)
      qf[h2][ks] = load8_scaled(
          q + ((size_t)(q0w + h2 * 16 + r) * H + h) * D + ks * 32 + g4 * 8, QSCALE);

  float m_[2] = {-1e30f, -1e30f};
  float l_[2] = {0.f, 0.f};            // lane-partial; reduced in epilogue
  f32x4 acc[2][4];
#pragma unroll
  for (int h2 = 0; h2 < 2; ++h2)
#pragma unroll
    for (int dc = 0; dc < 4; ++dc) acc[h2][dc] = f32x4{0.f, 0.f, 0.f, 0.f};

  // ---- staging: coalesced loads (256B / 16-lane group), reg-transposed V ----
  const int s16 = tid >> 4;        // constant within each 16-lane group
  const int s4  = (tid & 15) * 4;
  f32x4 lk[4], lv[4];
  auto stage_load = [&](int t) {
    const int kb = kb0 + t * BK;
#pragma unroll
    for (int u = 0; u < 4; ++u) {
      lk[u] = *reinterpret_cast<const f32x4*>(
          k + ((size_t)(kb + u * 16 + s16) * HKV + hkv) * D + s4);
      lv[u] = *reinterpret_cast<const f32x4*>(
          v + ((size_t)(kb + s16 * 4 + u) * HKV + hkv) * D + s4);
    }
  };
  auto stage_write = [&](int buf) {
#pragma unroll
    for (int u = 0; u < 4; ++u) {
      bf16x4 kw;
      kw[0] = (__bf16)lk[u][0]; kw[1] = (__bf16)lk[u][1];
      kw[2] = (__bf16)lk[u][2]; kw[3] = (__bf16)lk[u][3];
      *reinterpret_cast<bf16x4*>(&klds[buf][swz(u * 16 + s16, s4)]) = kw;
    }
#pragma unroll
    for (int j = 0; j < 4; ++j) {    // 4x4 in-register transpose of V
      bf16x4 vw;
      vw[0] = (__bf16)lv[0][j]; vw[1] = (__bf16)lv[1][j];
      vw[2] = (__bf16)lv[2][j]; vw[3] = (__bf16)lv[3][j];
      *reinterpret_cast<bf16x4*>(&vlds[buf][swz(s4 + j, s16 * 4)]) = vw;
    }
  };

  stage_load(0);
  stage_write(0);
  if (nt > 1) stage_load(1);
  __syncthreads();
  int cur = 0;

  for (int t = 0; t < nt; ++t) {
    const int kb = kb0 + t * BK;
    if (kb <= q0w + 31) {   // any row of wave unmasked
      // ---- S^T = K Q : lane owns score[key=kb+cg*16+g4*4+j][q] ----
      f32x4 sf[2][4];
      __builtin_amdgcn_s_setprio(1);
#pragma unroll
      for (int cg = 0; cg < 4; ++cg) {
        bf16x8 kf0 = *reinterpret_cast<const bf16x8*>(&klds[cur][swz(cg * 16 + r, g4 * 8)]);
        bf16x8 kf1 = *reinterpret_cast<const bf16x8*>(&klds[cur][swz(cg * 16 + r, 32 + g4 * 8)]);
#pragma unroll
        for (int h2 = 0; h2 < 2; ++h2) {
          f32x4 z = f32x4{0.f, 0.f, 0.f, 0.f};
          z = __builtin_amdgcn_mfma_f32_16x16x32_bf16(kf0, qf[h2][0], z, 0, 0, 0);
          z = __builtin_amdgcn_mfma_f32_16x16x32_bf16(kf1, qf[h2][1], z, 0, 0, 0);
          sf[h2][cg] = z;
        }
      }
      __builtin_amdgcn_s_setprio(0);

      // ---- per-half: softmax -> P into shared 16-row buffer -> PV ----
      // (same-wave DS ops execute in order: h2=1's P writes cannot pass
      //  h2=0's P reads, so reusing plds[wid] across halves is safe.)
#pragma unroll
      for (int h2 = 0; h2 < 2; ++h2) {
        const int qmin = q0w + h2 * 16;
        if (kb > qmin + 15) continue;        // wave-uniform: half fully masked
        if (kb + 63 > qmin) {                // causal mask needed
#pragma unroll
          for (int cg = 0; cg < 4; ++cg)
#pragma unroll
            for (int j = 0; j < 4; ++j)
              if (kb + cg * 16 + g4 * 4 + j > qmin + r) sf[h2][cg][j] = -1e30f;
        }
        float mxl = -1e30f;
#pragma unroll
        for (int cg = 0; cg < 4; ++cg)
          mxl = fmaxf(mxl, fmaxf(fmaxf(sf[h2][cg][0], sf[h2][cg][1]),
                                 fmaxf(sf[h2][cg][2], sf[h2][cg][3])));
        if (!__all(mxl - m_[h2] <= RTHR)) {  // T13 defer-max
          float mx = fmaxf(mxl, __shfl_xor(mxl, 16, 64));
          mx = fmaxf(mx, __shfl_xor(mx, 32, 64));
          const float mnew  = fmaxf(m_[h2], mx);
          const float alpha = exp2f(m_[h2] - mnew);
          l_[h2] *= alpha;
#pragma unroll
          for (int dc = 0; dc < 4; ++dc) acc[h2][dc] *= alpha;
          m_[h2] = mnew;
        }
        float ps = 0.f;
#pragma unroll
        for (int cg = 0; cg < 4; ++cg) {
          bf16x4 pw;
#pragma unroll
          for (int j = 0; j < 4; ++j) {
            const float p = exp2f(sf[h2][cg][j] - m_[h2]);
            ps += p;
            pw[j] = (__bf16)p;
          }
          *reinterpret_cast<bf16x4*>(&plds[wid][swz(r, cg * 16 + g4 * 4)]) = pw;
        }
        l_[h2] += ps;

        // ---- O^T += V^T P^T for this half ----
        __builtin_amdgcn_s_setprio(1);
#pragma unroll
        for (int ks = 0; ks < 2; ++ks) {
          bf16x8 pf = *reinterpret_cast<const bf16x8*>(
              &plds[wid][swz(r, ks * 32 + g4 * 8)]);
#pragma unroll
          for (int dc = 0; dc < 4; ++dc) {
            bf16x8 vf = *reinterpret_cast<const bf16x8*>(
                &vlds[cur][swz(dc * 16 + r, ks * 32 + g4 * 8)]);
            acc[h2][dc] = __builtin_amdgcn_mfma_f32_16x16x32_bf16(vf, pf, acc[h2][dc], 0, 0, 0);
          }
        }
        __builtin_amdgcn_s_setprio(0);
      }
    }

    if (t + 1 < nt) stage_write(cur ^ 1);  // regs from loads issued last iter
    if (t + 2 < nt) stage_load(t + 2);     // land during next tile's compute
    __syncthreads();
    cur ^= 1;
  }

  // ---- epilogue: reduce l once; everything else lane-local ----
#pragma unroll
  for (int h2 = 0; h2 < 2; ++h2) {
    float lsum = l_[h2];
    lsum += __shfl_xor(lsum, 16, 64);
    lsum += __shfl_xor(lsum, 32, 64);
    const int qrow = q0w + h2 * 16 + r;
    if (SPLIT) {
      __bf16* prow = po + ((size_t)(c * S_LEN + qrow) * H + h) * D;
#pragma unroll
      for (int dc = 0; dc < 4; ++dc) {
        bf16x4 pb;
        pb[0] = (__bf16)acc[h2][dc][0]; pb[1] = (__bf16)acc[h2][dc][1];
        pb[2] = (__bf16)acc[h2][dc][2]; pb[3] = (__bf16)acc[h2][dc][3];
        *reinterpret_cast<bf16x4*>(prow + dc * 16 + g4 * 4) = pb;
      }
      if (g4 == 0) {
        float* m2 = ml + ((size_t)(c * S_LEN + qrow) * H + h) * 2;
        m2[0] = m_[h2];
        m2[1] = lsum;
      }
    } else {
      const float inv = 1.0f / lsum;
      float* orow = out + ((size_t)qrow * H + h) * D;
#pragma unroll
      for (int dc = 0; dc < 4; ++dc) {
        f32x4 o;
        o[0] = acc[h2][dc][0] * inv; o[1] = acc[h2][dc][1] * inv;
        o[2] = acc[h2][dc][2] * inv; o[3] = acc[h2][dc][3] * inv;
        *reinterpret_cast<f32x4*>(orow + dc * 16 + g4 * 4) = o;
      }
    }
  }
}

// one wave per (row, head): merge partials (exp2 domain), normalize, store.
template <int LOG2C>
__global__ __launch_bounds__(256) void combine_kernel(
    const __bf16* __restrict__ po, const float* __restrict__ ml,
    float* __restrict__ out) {
  constexpr int NS = S_LEN >> LOG2C;
  const int lane = threadIdx.x & 63;
  const int widx = (blockIdx.x << 2) + (threadIdx.x >> 6);
  const int h    = widx & 7;
  const int row  = widx >> 3;
  const int cmax = row >> LOG2C;

  float mv[NS];
  float M = -1e30f;
#pragma unroll
  for (int cc = 0; cc < NS; ++cc) {
    mv[cc] = (cc <= cmax) ? ml[((size_t)(cc * S_LEN + row) * H + h) * 2] : -1e30f;
    M = fmaxf(M, mv[cc]);
  }
  float lsum = 0.f, osum = 0.f;
#pragma unroll
  for (int cc = 0; cc < NS; ++cc) {
    if (cc <= cmax) {
      const float w = exp2f(mv[cc] - M);
      lsum += w * ml[((size_t)(cc * S_LEN + row) * H + h) * 2 + 1];
      osum += w * (float)po[((size_t)(cc * S_LEN + row) * H + h) * D + lane];
    }
  }
  out[((size_t)row * H + h) * D + lane] = osum / lsum;
}

static int nwork_items(int log2c) {
  int s = 0;
  for (int qb = 0; qb < NQB; ++qb)
    s += ((qb * QB_ROWS + QB_ROWS - 1) >> log2c) + 1;
  return s;
}

extern "C" void kernel_launch(void* const* d_in, const int* in_sizes, int n_in,
                              void* d_out, int out_size, void* d_ws, size_t ws_size,
                              hipStream_t stream) {
  const float* q = (const float*)d_in[0];
  const float* k = (const float*)d_in[1];
  const float* v = (const float*)d_in[2];
  float* out = (float*)d_out;

  const size_t po8 = 8ull * S_LEN * H * D, ml8 = 8ull * S_LEN * H * 2;
  const size_t po4 = 4ull * S_LEN * H * D, ml4 = 4ull * S_LEN * H * 2;

  if (ws_size >= po8 * 2 + ml8 * 4) {         // bf16 po + f32 ml
    __bf16* po = (__bf16*)d_ws;
    float* ml = (float*)(po + po8);
    gqa_fwd_kernel<9, true><<<dim3(8 * nwork_items(9)), dim3(256), 0, stream>>>(
        q, k, v, out, po, ml);
    combine_kernel<9><<<dim3(S_LEN * H / 4), dim3(256), 0, stream>>>(po, ml, out);
  } else if (ws_size >= po4 * 2 + ml4 * 4) {
    __bf16* po = (__bf16*)d_ws;
    float* ml = (float*)(po + po4);
    gqa_fwd_kernel<10, true><<<dim3(8 * nwork_items(10)), dim3(256), 0, stream>>>(
        q, k, v, out, po, ml);
    combine_kernel<10><<<dim3(S_LEN * H / 4), dim3(256), 0, stream>>>(po, ml, out);
  } else {
    gqa_fwd_kernel<12, false><<<dim3(8 * nwork_items(12)), dim3(256), 0, stream>>>(
        q, k, v, out, nullptr, nullptr);
  }
}

// Round 7
// 70.068 us; speedup vs baseline: 2.3250x; 2.3250x over previous
//
#include <hip/hip_runtime.h>
#include <hip/hip_bf16.h>

typedef __attribute__((ext_vector_type(8))) __bf16 bf16x8;
typedef __attribute__((ext_vector_type(4))) __bf16 bf16x4;
typedef __attribute__((ext_vector_type(4))) float f32x4;

constexpr int S_LEN = 4096;
constexpr int H = 8;
constexpr int HKV = 2;
constexpr int D = 64;
constexpr int BK = 64;               // keys per tile
constexpr int QW = 32;               // q rows per wave (2 halves of 16)
constexpr int WAVES = 4;             // 128 q rows per block
constexpr int QB_ROWS = QW * WAVES;  // 128
constexpr int NQB = S_LEN / QB_ROWS; // 32
// exp2-domain: scores scaled by 1/sqrt(64) * log2(e)
constexpr float QSCALE = 0.125f * 1.44269504088896f;
constexpr float RTHR = 8.0f;         // defer-max threshold (log2 units)

// XOR swizzle for [*][64] bf16 tiles; f(row)=((row>>2)^row)&7 spreads both
// stride-1 and stride-4 row patterns across 8 16B slots. Preserves 16B chunks.
__device__ __forceinline__ int swz(int row, int col) {
  return (row * 64 + col) ^ ((((row >> 2) ^ row) & 7) << 3);
}

__device__ __forceinline__ bf16x8 load8_scaled(const float* p, float scale) {
  f32x4 a = *reinterpret_cast<const f32x4*>(p);
  f32x4 b = *reinterpret_cast<const f32x4*>(p + 4);
  bf16x8 r;
  r[0] = (__bf16)(a[0] * scale); r[1] = (__bf16)(a[1] * scale);
  r[2] = (__bf16)(a[2] * scale); r[3] = (__bf16)(a[3] * scale);
  r[4] = (__bf16)(b[0] * scale); r[5] = (__bf16)(b[1] * scale);
  r[6] = (__bf16)(b[2] * scale); r[7] = (__bf16)(b[3] * scale);
  return r;
}

// CHUNK = 1<<LOG2C keys per split chunk. Compact grid: widx enumerates
// (qb, c) pairs heavy-qb-first with exactly cmax(qb)+1 chunks per qb.
// launch_bounds(256,3): VGPR cap ~170 -> compiler uses ~85, NO SPILL.
// (256,4) capped VGPRs at 64 and spilled ~400MB/launch to scratch (R6).
template <int LOG2C, bool SPLIT>
__global__ __launch_bounds__(256, 3) void gqa_fwd_kernel(
    const float* __restrict__ q, const float* __restrict__ k,
    const float* __restrict__ v, float* __restrict__ out,
    __bf16* __restrict__ po, float* __restrict__ ml) {
  constexpr int TPC = (1 << LOG2C) / BK;  // tiles per full chunk

  const int tid  = threadIdx.x;
  const int lane = tid & 63;
  const int wid  = tid >> 6;
  const int r    = lane & 15;
  const int g4   = lane >> 4;

  const int h = blockIdx.x & 7;
  const int widx = blockIdx.x >> 3;
  int qb = 0, c = 0;
  {
    int acc0 = 0;
    for (int qq = NQB - 1; qq >= 0; --qq) {   // heavy q-blocks first
      const int n = ((qq * QB_ROWS + QB_ROWS - 1) >> LOG2C) + 1;
      if (widx < acc0 + n) { qb = qq; c = widx - acc0; break; }
      acc0 += n;
    }
  }
  const int cmax = (qb * QB_ROWS + QB_ROWS - 1) >> LOG2C;
  const int hkv = h >> 2;
  const int q0w = qb * QB_ROWS + wid * QW;            // wave's first q row
  const int nt  = (c < cmax) ? TPC : (2 * (qb + 1) - TPC * cmax);
  const int kb0 = c << LOG2C;

  __shared__ __bf16 klds[2][64 * 64];          // K tile [kv][d], swizzled
  __shared__ __bf16 vlds[2][64 * 64];          // V^T tile [d][kv], swizzled
  __shared__ __bf16 plds[WAVES][16 * 64];      // P^T scratch, reused per half

  // ---- Q B-fragments (held), pre-scaled into exp2 domain ----
  bf16x8 qf[2][2];
#pragma unroll
  for (int h2 = 0; h2 < 2; ++h2)
#pragma unroll
    for (int ks = 0; ks < 2; ++ks)
      qf[h2][ks] = load8_scaled(
          q + ((size_t)(q0w + h2 * 16 + r) * H + h) * D + ks * 32 + g4 * 8, QSCALE);

  float m_[2] = {-1e30f, -1e30f};
  float l_[2] = {0.f, 0.f};            // lane-partial; reduced in epilogue
  f32x4 acc[2][4];
#pragma unroll
  for (int h2 = 0; h2 < 2; ++h2)
#pragma unroll
    for (int dc = 0; dc < 4; ++dc) acc[h2][dc] = f32x4{0.f, 0.f, 0.f, 0.f};

  // ---- staging: coalesced loads (256B / 16-lane group), reg-transposed V ----
  const int s16 = tid >> 4;        // constant within each 16-lane group
  const int s4  = (tid & 15) * 4;
  f32x4 lk[4], lv[4];
  auto stage_load = [&](int t) {
    const int kb = kb0 + t * BK;
#pragma unroll
    for (int u = 0; u < 4; ++u) {
      lk[u] = *reinterpret_cast<const f32x4*>(
          k + ((size_t)(kb + u * 16 + s16) * HKV + hkv) * D + s4);
      lv[u] = *reinterpret_cast<const f32x4*>(
          v + ((size_t)(kb + s16 * 4 + u) * HKV + hkv) * D + s4);
    }
  };
  auto stage_write = [&](int buf) {
#pragma unroll
    for (int u = 0; u < 4; ++u) {
      bf16x4 kw;
      kw[0] = (__bf16)lk[u][0]; kw[1] = (__bf16)lk[u][1];
      kw[2] = (__bf16)lk[u][2]; kw[3] = (__bf16)lk[u][3];
      *reinterpret_cast<bf16x4*>(&klds[buf][swz(u * 16 + s16, s4)]) = kw;
    }
#pragma unroll
    for (int j = 0; j < 4; ++j) {    // 4x4 in-register transpose of V
      bf16x4 vw;
      vw[0] = (__bf16)lv[0][j]; vw[1] = (__bf16)lv[1][j];
      vw[2] = (__bf16)lv[2][j]; vw[3] = (__bf16)lv[3][j];
      *reinterpret_cast<bf16x4*>(&vlds[buf][swz(s4 + j, s16 * 4)]) = vw;
    }
  };

  stage_load(0);
  stage_write(0);
  if (nt > 1) stage_load(1);
  __syncthreads();
  int cur = 0;

  for (int t = 0; t < nt; ++t) {
    const int kb = kb0 + t * BK;
    if (kb <= q0w + 31) {   // any row of wave unmasked
      // ---- S^T = K Q : lane owns score[key=kb+cg*16+g4*4+j][q] ----
      f32x4 sf[2][4];
      __builtin_amdgcn_s_setprio(1);
#pragma unroll
      for (int cg = 0; cg < 4; ++cg) {
        bf16x8 kf0 = *reinterpret_cast<const bf16x8*>(&klds[cur][swz(cg * 16 + r, g4 * 8)]);
        bf16x8 kf1 = *reinterpret_cast<const bf16x8*>(&klds[cur][swz(cg * 16 + r, 32 + g4 * 8)]);
#pragma unroll
        for (int h2 = 0; h2 < 2; ++h2) {
          f32x4 z = f32x4{0.f, 0.f, 0.f, 0.f};
          z = __builtin_amdgcn_mfma_f32_16x16x32_bf16(kf0, qf[h2][0], z, 0, 0, 0);
          z = __builtin_amdgcn_mfma_f32_16x16x32_bf16(kf1, qf[h2][1], z, 0, 0, 0);
          sf[h2][cg] = z;
        }
      }
      __builtin_amdgcn_s_setprio(0);

      // ---- per-half: softmax -> P into shared 16-row buffer -> PV ----
      // (same-wave DS ops execute in order: h2=1's P writes cannot pass
      //  h2=0's P reads, so reusing plds[wid] across halves is safe.)
#pragma unroll
      for (int h2 = 0; h2 < 2; ++h2) {
        const int qmin = q0w + h2 * 16;
        if (kb > qmin + 15) continue;        // wave-uniform: half fully masked
        if (kb + 63 > qmin) {                // causal mask needed
#pragma unroll
          for (int cg = 0; cg < 4; ++cg)
#pragma unroll
            for (int j = 0; j < 4; ++j)
              if (kb + cg * 16 + g4 * 4 + j > qmin + r) sf[h2][cg][j] = -1e30f;
        }
        float mxl = -1e30f;
#pragma unroll
        for (int cg = 0; cg < 4; ++cg)
          mxl = fmaxf(mxl, fmaxf(fmaxf(sf[h2][cg][0], sf[h2][cg][1]),
                                 fmaxf(sf[h2][cg][2], sf[h2][cg][3])));
        if (!__all(mxl - m_[h2] <= RTHR)) {  // T13 defer-max
          float mx = fmaxf(mxl, __shfl_xor(mxl, 16, 64));
          mx = fmaxf(mx, __shfl_xor(mx, 32, 64));
          const float mnew  = fmaxf(m_[h2], mx);
          const float alpha = exp2f(m_[h2] - mnew);
          l_[h2] *= alpha;
#pragma unroll
          for (int dc = 0; dc < 4; ++dc) acc[h2][dc] *= alpha;
          m_[h2] = mnew;
        }
        float ps = 0.f;
#pragma unroll
        for (int cg = 0; cg < 4; ++cg) {
          bf16x4 pw;
#pragma unroll
          for (int j = 0; j < 4; ++j) {
            const float p = exp2f(sf[h2][cg][j] - m_[h2]);
            ps += p;
            pw[j] = (__bf16)p;
          }
          *reinterpret_cast<bf16x4*>(&plds[wid][swz(r, cg * 16 + g4 * 4)]) = pw;
        }
        l_[h2] += ps;

        // ---- O^T += V^T P^T for this half ----
        __builtin_amdgcn_s_setprio(1);
#pragma unroll
        for (int ks = 0; ks < 2; ++ks) {
          bf16x8 pf = *reinterpret_cast<const bf16x8*>(
              &plds[wid][swz(r, ks * 32 + g4 * 8)]);
#pragma unroll
          for (int dc = 0; dc < 4; ++dc) {
            bf16x8 vf = *reinterpret_cast<const bf16x8*>(
                &vlds[cur][swz(dc * 16 + r, ks * 32 + g4 * 8)]);
            acc[h2][dc] = __builtin_amdgcn_mfma_f32_16x16x32_bf16(vf, pf, acc[h2][dc], 0, 0, 0);
          }
        }
        __builtin_amdgcn_s_setprio(0);
      }
    }

    if (t + 1 < nt) stage_write(cur ^ 1);  // regs from loads issued last iter
    if (t + 2 < nt) stage_load(t + 2);     // land during next tile's compute
    __syncthreads();
    cur ^= 1;
  }

  // ---- epilogue: reduce l once; everything else lane-local ----
#pragma unroll
  for (int h2 = 0; h2 < 2; ++h2) {
    float lsum = l_[h2];
    lsum += __shfl_xor(lsum, 16, 64);
    lsum += __shfl_xor(lsum, 32, 64);
    const int qrow = q0w + h2 * 16 + r;
    if (SPLIT) {
      __bf16* prow = po + ((size_t)(c * S_LEN + qrow) * H + h) * D;
#pragma unroll
      for (int dc = 0; dc < 4; ++dc) {
        bf16x4 pb;
        pb[0] = (__bf16)acc[h2][dc][0]; pb[1] = (__bf16)acc[h2][dc][1];
        pb[2] = (__bf16)acc[h2][dc][2]; pb[3] = (__bf16)acc[h2][dc][3];
        *reinterpret_cast<bf16x4*>(prow + dc * 16 + g4 * 4) = pb;
      }
      if (g4 == 0) {
        float* m2 = ml + ((size_t)(c * S_LEN + qrow) * H + h) * 2;
        m2[0] = m_[h2];
        m2[1] = lsum;
      }
    } else {
      const float inv = 1.0f / lsum;
      float* orow = out + ((size_t)qrow * H + h) * D;
#pragma unroll
      for (int dc = 0; dc < 4; ++dc) {
        f32x4 o;
        o[0] = acc[h2][dc][0] * inv; o[1] = acc[h2][dc][1] * inv;
        o[2] = acc[h2][dc][2] * inv; o[3] = acc[h2][dc][3] * inv;
        *reinterpret_cast<f32x4*>(orow + dc * 16 + g4 * 4) = o;
      }
    }
  }
}

// one wave per (row, head): merge partials (exp2 domain), normalize, store.
template <int LOG2C>
__global__ __launch_bounds__(256) void combine_kernel(
    const __bf16* __restrict__ po, const float* __restrict__ ml,
    float* __restrict__ out) {
  constexpr int NS = S_LEN >> LOG2C;
  const int lane = threadIdx.x & 63;
  const int widx = (blockIdx.x << 2) + (threadIdx.x >> 6);
  const int h    = widx & 7;
  const int row  = widx >> 3;
  const int cmax = row >> LOG2C;

  float mv[NS];
  float M = -1e30f;
#pragma unroll
  for (int cc = 0; cc < NS; ++cc) {
    mv[cc] = (cc <= cmax) ? ml[((size_t)(cc * S_LEN + row) * H + h) * 2] : -1e30f;
    M = fmaxf(M, mv[cc]);
  }
  float lsum = 0.f, osum = 0.f;
#pragma unroll
  for (int cc = 0; cc < NS; ++cc) {
    if (cc <= cmax) {
      const float w = exp2f(mv[cc] - M);
      lsum += w * ml[((size_t)(cc * S_LEN + row) * H + h) * 2 + 1];
      osum += w * (float)po[((size_t)(cc * S_LEN + row) * H + h) * D + lane];
    }
  }
  out[((size_t)row * H + h) * D + lane] = osum / lsum;
}

static int nwork_items(int log2c) {
  int s = 0;
  for (int qb = 0; qb < NQB; ++qb)
    s += ((qb * QB_ROWS + QB_ROWS - 1) >> log2c) + 1;
  return s;
}

extern "C" void kernel_launch(void* const* d_in, const int* in_sizes, int n_in,
                              void* d_out, int out_size, void* d_ws, size_t ws_size,
                              hipStream_t stream) {
  const float* q = (const float*)d_in[0];
  const float* k = (const float*)d_in[1];
  const float* v = (const float*)d_in[2];
  float* out = (float*)d_out;

  const size_t po8 = 8ull * S_LEN * H * D, ml8 = 8ull * S_LEN * H * 2;
  const size_t po4 = 4ull * S_LEN * H * D, ml4 = 4ull * S_LEN * H * 2;

  if (ws_size >= po8 * 2 + ml8 * 4) {         // bf16 po + f32 ml
    __bf16* po = (__bf16*)d_ws;
    float* ml = (float*)(po + po8);
    gqa_fwd_kernel<9, true><<<dim3(8 * nwork_items(9)), dim3(256), 0, stream>>>(
        q, k, v, out, po, ml);
    combine_kernel<9><<<dim3(S_LEN * H / 4), dim3(256), 0, stream>>>(po, ml, out);
  } else if (ws_size >= po4 * 2 + ml4 * 4) {
    __bf16* po = (__bf16*)d_ws;
    float* ml = (float*)(po + po4);
    gqa_fwd_kernel<10, true><<<dim3(8 * nwork_items(10)), dim3(256), 0, stream>>>(
        q, k, v, out, po, ml);
    combine_kernel<10><<<dim3(S_LEN * H / 4), dim3(256), 0, stream>>>(po, ml, out);
  } else {
    gqa_fwd_kernel<12, false><<<dim3(8 * nwork_items(12)), dim3(256), 0, stream>>>(
        q, k, v, out, nullptr, nullptr);
  }
}